// Round 7
// baseline (22024.446 us; speedup 1.0000x reference)
//
#include <hip/hip_runtime.h>
#include <hip/hip_cooperative_groups.h>
#include <math.h>

namespace cg = cooperative_groups;

#define NT 64
#define NB 1024
#define NC 512
#define HH 512
#define EE 128
#define NCLS 97
#define STEPS 32

__device__ __forceinline__ float fast_tanh(float x) {
  float e = __expf(2.f * x);
  return 1.f - 2.f / (e + 1.f);
}
__device__ __forceinline__ float fast_sig(float x) {
  return 1.f / (1.f + __expf(-x));
}

// ---------------- big GEMM: C[M,N] = A[M,K] @ B[N,K]^T
// 128(M)x256(N) tile, 8x16 micro, split fragments (2-way-max LDS banks)
__global__ __launch_bounds__(256) void gemm_bt_big(
    const float* __restrict__ A, const float* __restrict__ B,
    float* __restrict__ C, int M, int N, int K) {
  __shared__ float As[16][132];
  __shared__ float Bs[16][260];
  const int bm = blockIdx.y * 128;
  const int bn = blockIdx.x * 256;
  const int tid = threadIdx.x;
  const int tx = tid & 15, ty = tid >> 4;
  const int sr = tid >> 1;       // 0..127
  const int sk = (tid & 1) * 8;  // 0 or 8
  float acc[8][16];
#pragma unroll
  for (int i = 0; i < 8; ++i)
#pragma unroll
    for (int j = 0; j < 16; ++j) acc[i][j] = 0.f;
  const float* Ap = A + (size_t)(bm + sr) * K + sk;
  const float* Bp0 = B + (size_t)(bn + sr) * K + sk;
  const float* Bp1 = B + (size_t)(bn + 128 + sr) * K + sk;
  for (int k0 = 0; k0 < K; k0 += 16) {
    float4 a0 = *(const float4*)(Ap + k0);
    float4 a1 = *(const float4*)(Ap + k0 + 4);
    float4 b00 = *(const float4*)(Bp0 + k0);
    float4 b01 = *(const float4*)(Bp0 + k0 + 4);
    float4 b10 = *(const float4*)(Bp1 + k0);
    float4 b11 = *(const float4*)(Bp1 + k0 + 4);
    As[sk + 0][sr] = a0.x; As[sk + 1][sr] = a0.y;
    As[sk + 2][sr] = a0.z; As[sk + 3][sr] = a0.w;
    As[sk + 4][sr] = a1.x; As[sk + 5][sr] = a1.y;
    As[sk + 6][sr] = a1.z; As[sk + 7][sr] = a1.w;
    Bs[sk + 0][sr] = b00.x; Bs[sk + 1][sr] = b00.y;
    Bs[sk + 2][sr] = b00.z; Bs[sk + 3][sr] = b00.w;
    Bs[sk + 4][sr] = b01.x; Bs[sk + 5][sr] = b01.y;
    Bs[sk + 6][sr] = b01.z; Bs[sk + 7][sr] = b01.w;
    Bs[sk + 0][128 + sr] = b10.x; Bs[sk + 1][128 + sr] = b10.y;
    Bs[sk + 2][128 + sr] = b10.z; Bs[sk + 3][128 + sr] = b10.w;
    Bs[sk + 4][128 + sr] = b11.x; Bs[sk + 5][128 + sr] = b11.y;
    Bs[sk + 6][128 + sr] = b11.z; Bs[sk + 7][128 + sr] = b11.w;
    __syncthreads();
#pragma unroll
    for (int kk = 0; kk < 16; ++kk) {
      float a[8], b[16];
      *(float4*)&a[0] = *(const float4*)&As[kk][ty * 4];
      *(float4*)&a[4] = *(const float4*)&As[kk][64 + ty * 4];
      *(float4*)&b[0] = *(const float4*)&Bs[kk][tx * 4];
      *(float4*)&b[4] = *(const float4*)&Bs[kk][64 + tx * 4];
      *(float4*)&b[8] = *(const float4*)&Bs[kk][128 + tx * 4];
      *(float4*)&b[12] = *(const float4*)&Bs[kk][192 + tx * 4];
#pragma unroll
      for (int i = 0; i < 8; ++i)
#pragma unroll
        for (int j = 0; j < 16; ++j) acc[i][j] += a[i] * b[j];
    }
    __syncthreads();
  }
#pragma unroll
  for (int ig = 0; ig < 2; ++ig)
#pragma unroll
    for (int i = 0; i < 4; ++i) {
      int row = bm + ig * 64 + ty * 4 + i;
      int ai = ig * 4 + i;
#pragma unroll
      for (int jg = 0; jg < 4; ++jg) {
        float4 o;
        o.x = acc[ai][jg * 4 + 0];
        o.y = acc[ai][jg * 4 + 1];
        o.z = acc[ai][jg * 4 + 2];
        o.w = acc[ai][jg * 4 + 3];
        *(float4*)(C + (size_t)row * N + bn + jg * 64 + tx * 4) = o;
      }
    }
}

// ---------------- shared LDS union for the persistent kernel
union LdsU {
  struct { float As[16][66]; float Bs[16][132]; } g;
  struct { float es[NT]; float als[NT]; } a;
  struct { float hs[HH]; float lv[256]; int li[256]; } u;
};

// 64(M)x128(N) tile, K fixed 256 (one K-half), 4x8 micro split-col
__device__ __forceinline__ void gemm_phase(
    LdsU* lds, const float* __restrict__ A, int lda,
    const float* __restrict__ B, int ldb, const float* __restrict__ bias,
    float* __restrict__ C, int ldc, int bm, int bn, int kbase) {
  const int tid = threadIdx.x;
  const int tx = tid & 15, ty = tid >> 4;
  const int ar = tid >> 2, ak = (tid & 3) * 4;
  const int br = tid >> 1, bk = (tid & 1) * 8;
  float acc[4][8];
#pragma unroll
  for (int i = 0; i < 4; ++i)
#pragma unroll
    for (int j = 0; j < 8; ++j) acc[i][j] = 0.f;
  const float* Ap = A + (size_t)(bm + ar) * lda + kbase + ak;
  const float* Bp = B + (size_t)(bn + br) * ldb + kbase + bk;
  for (int k0 = 0; k0 < 256; k0 += 16) {
    float4 av = *(const float4*)(Ap + k0);
    float4 b0 = *(const float4*)(Bp + k0);
    float4 b1 = *(const float4*)(Bp + k0 + 4);
    lds->g.As[ak + 0][ar] = av.x; lds->g.As[ak + 1][ar] = av.y;
    lds->g.As[ak + 2][ar] = av.z; lds->g.As[ak + 3][ar] = av.w;
    lds->g.Bs[bk + 0][br] = b0.x; lds->g.Bs[bk + 1][br] = b0.y;
    lds->g.Bs[bk + 2][br] = b0.z; lds->g.Bs[bk + 3][br] = b0.w;
    lds->g.Bs[bk + 4][br] = b1.x; lds->g.Bs[bk + 5][br] = b1.y;
    lds->g.Bs[bk + 6][br] = b1.z; lds->g.Bs[bk + 7][br] = b1.w;
    __syncthreads();
#pragma unroll
    for (int kk = 0; kk < 16; ++kk) {
      float a[4], b[8];
      *(float4*)&a[0] = *(const float4*)&lds->g.As[kk][ty * 4];
      *(float4*)&b[0] = *(const float4*)&lds->g.Bs[kk][tx * 4];
      *(float4*)&b[4] = *(const float4*)&lds->g.Bs[kk][64 + tx * 4];
#pragma unroll
      for (int i = 0; i < 4; ++i)
#pragma unroll
        for (int j = 0; j < 8; ++j) acc[i][j] += a[i] * b[j];
    }
    __syncthreads();
  }
  float bc0[4] = {0.f, 0.f, 0.f, 0.f};
  float bc1[4] = {0.f, 0.f, 0.f, 0.f};
  if (bias) {
    *(float4*)bc0 = *(const float4*)(bias + bn + tx * 4);
    *(float4*)bc1 = *(const float4*)(bias + bn + 64 + tx * 4);
  }
#pragma unroll
  for (int i = 0; i < 4; ++i) {
    int row = bm + ty * 4 + i;
    float4 o0, o1;
    o0.x = acc[i][0] + bc0[0]; o0.y = acc[i][1] + bc0[1];
    o0.z = acc[i][2] + bc0[2]; o0.w = acc[i][3] + bc0[3];
    o1.x = acc[i][4] + bc1[0]; o1.y = acc[i][5] + bc1[1];
    o1.z = acc[i][6] + bc1[2]; o1.w = acc[i][7] + bc1[3];
    *(float4*)(C + (size_t)row * ldc + bn + tx * 4) = o0;
    *(float4*)(C + (size_t)row * ldc + bn + 64 + tx * 4) = o1;
  }
}

// ---------------- persistent cooperative step loop: 512 blocks x 256 thr
__global__ __launch_bounds__(256, 2) void step_loop(
    const float* __restrict__ fp, float* __restrict__ C1a,
    float* __restrict__ C1b, float* __restrict__ Ga, float* __restrict__ Gb,
    float* __restrict__ context, float* __restrict__ h0,
    float* __restrict__ h1, const float* __restrict__ Wcat,
    const float* __restrict__ bcat, const float* __restrict__ P,
    const float* __restrict__ w_ih, const float* __restrict__ w_score,
    const float* __restrict__ feats, const float* __restrict__ w_gen,
    const float* __restrict__ b_gen, const int* __restrict__ tl,
    const int* __restrict__ offs, float* __restrict__ out,
    int* __restrict__ tgt) {
  __shared__ LdsU lds;
  cg::grid_group grid = cg::this_grid();
  const int bid = blockIdx.x;
  const int tid = threadIdx.x;

  for (int s = 0; s < STEPS; ++s) {
    const float* hc = (s & 1) ? h1 : h0;
    float* hn = (s & 1) ? h0 : h1;

    // ---- phase 1: C1 = hc @ Wcat^T + bcat  [1024,2048], Ksplit2 = 512 tiles
    {
      int kh = bid >> 8;
      int r = bid & 255;
      gemm_phase(&lds, hc, HH, Wcat, 512, (kh == 0) ? bcat : nullptr,
                 kh ? C1b : C1a, 2048, (r >> 4) * 64, (r & 15) * 128,
                 kh * 256);
    }
    __threadfence();
    grid.sync();

    // ---- phase 2: e + softmax + context, 2 batches per block
    for (int half = 0; half < 2; ++half) {
      const int b = bid + half * 512;
      __syncthreads();
      const int lane = tid & 63, wid = tid >> 6;
      const float* hpa = C1a + (size_t)b * 2048 + lane * 8;
      const float* hpb = C1b + (size_t)b * 2048 + lane * 8;
      float4 ha0 = *(const float4*)hpa;
      float4 ha1 = *(const float4*)(hpa + 4);
      float4 hb0 = *(const float4*)hpb;
      float4 hb1 = *(const float4*)(hpb + 4);
      float4 h0v, h1v;
      h0v.x = ha0.x + hb0.x; h0v.y = ha0.y + hb0.y;
      h0v.z = ha0.z + hb0.z; h0v.w = ha0.w + hb0.w;
      h1v.x = ha1.x + hb1.x; h1v.y = ha1.y + hb1.y;
      h1v.z = ha1.z + hb1.z; h1v.w = ha1.w + hb1.w;
      float4 w0 = *(const float4*)(w_score + lane * 8);
      float4 w1 = *(const float4*)(w_score + lane * 8 + 4);
#pragma unroll
      for (int pass = 0; pass < 4; ++pass) {
        float4 f0[4], f1[4];
#pragma unroll
        for (int i = 0; i < 4; ++i) {
          int t = wid * 16 + pass * 4 + i;
          const float* fr = fp + ((size_t)t * NB + b) * HH + lane * 8;
          f0[i] = *(const float4*)fr;
          f1[i] = *(const float4*)(fr + 4);
        }
#pragma unroll
        for (int i = 0; i < 4; ++i) {
          float acc = 0.f;
          acc += fast_tanh(f0[i].x + h0v.x) * w0.x;
          acc += fast_tanh(f0[i].y + h0v.y) * w0.y;
          acc += fast_tanh(f0[i].z + h0v.z) * w0.z;
          acc += fast_tanh(f0[i].w + h0v.w) * w0.w;
          acc += fast_tanh(f1[i].x + h1v.x) * w1.x;
          acc += fast_tanh(f1[i].y + h1v.y) * w1.y;
          acc += fast_tanh(f1[i].z + h1v.z) * w1.z;
          acc += fast_tanh(f1[i].w + h1v.w) * w1.w;
#pragma unroll
          for (int off = 32; off > 0; off >>= 1)
            acc += __shfl_down(acc, off, 64);
          if (lane == 0) lds.a.es[wid * 16 + pass * 4 + i] = acc;
        }
      }
      __syncthreads();
      if (tid < 64) {
        float v = lds.a.es[tid];
        float mx = v;
#pragma unroll
        for (int off = 32; off > 0; off >>= 1)
          mx = fmaxf(mx, __shfl_xor(mx, off, 64));
        float p = __expf(v - mx);
        float sum = p;
#pragma unroll
        for (int off = 32; off > 0; off >>= 1) sum += __shfl_xor(sum, off, 64);
        lds.a.als[tid] = p / sum;
      }
      __syncthreads();
#pragma unroll
      for (int cc = 0; cc < 2; ++cc) {
        int c = tid + cc * 256;
        float a0 = 0.f, a1 = 0.f, a2 = 0.f, a3 = 0.f;
        const float* fb = feats + (size_t)b * NC + c;
#pragma unroll 4
        for (int t = 0; t < NT; t += 4) {
          a0 += lds.a.als[t + 0] * fb[(size_t)(t + 0) * NB * NC];
          a1 += lds.a.als[t + 1] * fb[(size_t)(t + 1) * NB * NC];
          a2 += lds.a.als[t + 2] * fb[(size_t)(t + 2) * NB * NC];
          a3 += lds.a.als[t + 3] * fb[(size_t)(t + 3) * NB * NC];
        }
        context[(size_t)b * NC + c] = ((a0 + a1) + (a2 + a3));
      }
      __syncthreads();
    }
    __threadfence();
    grid.sync();

    // ---- phase 3: gi = context @ w_ih[:, :512]^T  [1024,1536], Ksplit2
    if (bid < 384) {
      int kh = bid / 192;
      int r = bid % 192;
      gemm_phase(&lds, context, NC, w_ih, NC + EE, nullptr, kh ? Gb : Ga,
                 1536, (r / 12) * 64, (r % 12) * 128, kh * 256);
    }
    __threadfence();
    grid.sync();

    // ---- phase 4: GRU gates + logits + argmax, 2 batches per block
    for (int half = 0; half < 2; ++half) {
      const int b = bid + half * 512;
      __syncthreads();
      const int tg = tgt[b];
      const float* gia = Ga + (size_t)b * 1536;
      const float* gib = Gb + (size_t)b * 1536;
      const float* Pb = P + (size_t)tg * 1536;
      const float* gha = C1a + (size_t)b * 2048 + 512;
      const float* ghb = C1b + (size_t)b * 2048 + 512;
#pragma unroll
      for (int i = 0; i < 2; ++i) {
        int j = tid + i * 256;
        float ir = gia[j] + gib[j] + Pb[j];
        float iz = gia[512 + j] + gib[512 + j] + Pb[512 + j];
        float in = gia[1024 + j] + gib[1024 + j] + Pb[1024 + j];
        float hr = gha[j] + ghb[j];
        float hz = gha[512 + j] + ghb[512 + j];
        float hnv = gha[1024 + j] + ghb[1024 + j];
        float r = fast_sig(ir + hr);
        float z = fast_sig(iz + hz);
        float n = fast_tanh(in + r * hnv);
        float h = hc[(size_t)b * HH + j];
        float hv = (1.f - z) * n + z * h;
        lds.u.hs[j] = hv;
        hn[(size_t)b * HH + j] = hv;
      }
      __syncthreads();
      float acc = -INFINITY;
      if (tid < NCLS) {
        const float4* wr4 = (const float4*)(w_gen + (size_t)tid * HH);
        float sdot = 0.f;
        for (int k = 0; k < HH / 4; ++k) {
          float4 w = wr4[k];
          sdot += lds.u.hs[4 * k + 0] * w.x + lds.u.hs[4 * k + 1] * w.y +
                  lds.u.hs[4 * k + 2] * w.z + lds.u.hs[4 * k + 3] * w.w;
        }
        acc = sdot + b_gen[tid];
        if (s < tl[b]) out[(size_t)(offs[b] + s) * NCLS + tid] = acc;
      }
      lds.u.lv[tid] = acc;
      lds.u.li[tid] = tid;
      __syncthreads();
      for (int d = 128; d > 0; d >>= 1) {
        if (tid < d) {
          float v2 = lds.u.lv[tid + d];
          int i2 = lds.u.li[tid + d];
          if (v2 > lds.u.lv[tid] ||
              (v2 == lds.u.lv[tid] && i2 < lds.u.li[tid])) {
            lds.u.lv[tid] = v2;
            lds.u.li[tid] = i2;
          }
        }
        __syncthreads();
      }
      if (tid == 0) tgt[b] = lds.u.li[0] + 1;
      __syncthreads();
    }
    __threadfence();
    grid.sync();
  }
}

// ---------------- fallback (R5-verified) step kernels ----------------
__global__ __launch_bounds__(256) void gemm_bt_ks(
    const float* __restrict__ A, int lda, const float* __restrict__ B, int ldb,
    const float* __restrict__ bias, float* __restrict__ Ca,
    float* __restrict__ Cb, int ldc) {
  __shared__ LdsU lds;
  const int kh = blockIdx.z;
  gemm_phase(&lds, A, lda, B, ldb, (bias && kh == 0) ? bias : nullptr,
             kh ? Cb : Ca, ldc, blockIdx.y * 64, blockIdx.x * 128, kh * 256);
}

__global__ __launch_bounds__(512) void step_attn2(
    const float* __restrict__ fp, const float* __restrict__ C1a,
    const float* __restrict__ C1b, const float* __restrict__ w_score,
    const float* __restrict__ feats, float* __restrict__ context) {
  __shared__ float es[NT];
  __shared__ float als[NT];
  const int b = blockIdx.x;
  const int tid = threadIdx.x;
  const int lane = tid & 63, wid = tid >> 6;
  const float* hpa = C1a + (size_t)b * 2048 + lane * 8;
  const float* hpb = C1b + (size_t)b * 2048 + lane * 8;
  float4 ha0 = *(const float4*)hpa;
  float4 ha1 = *(const float4*)(hpa + 4);
  float4 hb0 = *(const float4*)hpb;
  float4 hb1 = *(const float4*)(hpb + 4);
  float4 h0, h1;
  h0.x = ha0.x + hb0.x; h0.y = ha0.y + hb0.y;
  h0.z = ha0.z + hb0.z; h0.w = ha0.w + hb0.w;
  h1.x = ha1.x + hb1.x; h1.y = ha1.y + hb1.y;
  h1.z = ha1.z + hb1.z; h1.w = ha1.w + hb1.w;
  float4 w0 = *(const float4*)(w_score + lane * 8);
  float4 w1 = *(const float4*)(w_score + lane * 8 + 4);
#pragma unroll
  for (int pass = 0; pass < 2; ++pass) {
    float4 f0[4], f1[4];
#pragma unroll
    for (int i = 0; i < 4; ++i) {
      int t = wid * 8 + pass * 4 + i;
      const float* fr = fp + ((size_t)t * NB + b) * HH + lane * 8;
      f0[i] = *(const float4*)fr;
      f1[i] = *(const float4*)(fr + 4);
    }
#pragma unroll
    for (int i = 0; i < 4; ++i) {
      float acc = 0.f;
      acc += fast_tanh(f0[i].x + h0.x) * w0.x;
      acc += fast_tanh(f0[i].y + h0.y) * w0.y;
      acc += fast_tanh(f0[i].z + h0.z) * w0.z;
      acc += fast_tanh(f0[i].w + h0.w) * w0.w;
      acc += fast_tanh(f1[i].x + h1.x) * w1.x;
      acc += fast_tanh(f1[i].y + h1.y) * w1.y;
      acc += fast_tanh(f1[i].z + h1.z) * w1.z;
      acc += fast_tanh(f1[i].w + h1.w) * w1.w;
#pragma unroll
      for (int off = 32; off > 0; off >>= 1) acc += __shfl_down(acc, off, 64);
      if (lane == 0) es[wid * 8 + pass * 4 + i] = acc;
    }
  }
  __syncthreads();
  if (tid < 64) {
    float v = es[tid];
    float mx = v;
#pragma unroll
    for (int off = 32; off > 0; off >>= 1) mx = fmaxf(mx, __shfl_xor(mx, off, 64));
    float p = __expf(v - mx);
    float sum = p;
#pragma unroll
    for (int off = 32; off > 0; off >>= 1) sum += __shfl_xor(sum, off, 64);
    als[tid] = p / sum;
  }
  __syncthreads();
  float a0 = 0.f, a1 = 0.f, a2 = 0.f, a3 = 0.f;
  const float* fb = feats + (size_t)b * NC + tid;
#pragma unroll 4
  for (int t = 0; t < NT; t += 4) {
    a0 += als[t + 0] * fb[(size_t)(t + 0) * NB * NC];
    a1 += als[t + 1] * fb[(size_t)(t + 1) * NB * NC];
    a2 += als[t + 2] * fb[(size_t)(t + 2) * NB * NC];
    a3 += als[t + 3] * fb[(size_t)(t + 3) * NB * NC];
  }
  context[(size_t)b * NC + tid] = ((a0 + a1) + (a2 + a3));
}

__global__ __launch_bounds__(128) void step_update2(
    const float* __restrict__ C1a, const float* __restrict__ C1b,
    const float* __restrict__ Ga, const float* __restrict__ Gb,
    const float* __restrict__ P, const float* __restrict__ hc,
    float* __restrict__ hn_out, const float* __restrict__ w_gen,
    const float* __restrict__ b_gen, const int* __restrict__ tl,
    const int* __restrict__ offs, float* __restrict__ out,
    int* __restrict__ tgt, int step) {
  __shared__ float hs[HH];
  __shared__ float lv[128];
  __shared__ int li[128];
  const int b = blockIdx.x;
  const int tid = threadIdx.x;
  const int tg = tgt[b];
  const float* gia = Ga + (size_t)b * 1536;
  const float* gib = Gb + (size_t)b * 1536;
  const float* Pb = P + (size_t)tg * 1536;
  const float* gha = C1a + (size_t)b * 2048 + 512;
  const float* ghb = C1b + (size_t)b * 2048 + 512;
#pragma unroll
  for (int i = 0; i < 4; ++i) {
    int j = tid + i * 128;
    float ir = gia[j] + gib[j] + Pb[j];
    float iz = gia[512 + j] + gib[512 + j] + Pb[512 + j];
    float in = gia[1024 + j] + gib[1024 + j] + Pb[1024 + j];
    float hr = gha[j] + ghb[j];
    float hz = gha[512 + j] + ghb[512 + j];
    float hnv = gha[1024 + j] + ghb[1024 + j];
    float r = fast_sig(ir + hr);
    float z = fast_sig(iz + hz);
    float n = fast_tanh(in + r * hnv);
    float h = hc[(size_t)b * HH + j];
    float hv = (1.f - z) * n + z * h;
    hs[j] = hv;
    hn_out[(size_t)b * HH + j] = hv;
  }
  __syncthreads();
  float acc = -INFINITY;
  if (tid < NCLS) {
    const float4* wr4 = (const float4*)(w_gen + (size_t)tid * HH);
    float s = 0.f;
    for (int k = 0; k < HH / 4; ++k) {
      float4 w = wr4[k];
      s += hs[4 * k + 0] * w.x + hs[4 * k + 1] * w.y +
           hs[4 * k + 2] * w.z + hs[4 * k + 3] * w.w;
    }
    acc = s + b_gen[tid];
    if (step < tl[b]) out[(size_t)(offs[b] + step) * NCLS + tid] = acc;
  }
  lv[tid] = acc;
  li[tid] = tid;
  __syncthreads();
  for (int d = 64; d > 0; d >>= 1) {
    if (tid < d) {
      float v2 = lv[tid + d];
      int i2 = li[tid + d];
      if (v2 > lv[tid] || (v2 == lv[tid] && i2 < li[tid])) {
        lv[tid] = v2;
        li[tid] = i2;
      }
    }
    __syncthreads();
  }
  if (tid == 0) tgt[b] = li[0] + 1;
}

// ---------------- one-time setup kernels
__global__ __launch_bounds__(256) void build_P(
    const float* __restrict__ char_emb, const float* __restrict__ w_ih,
    const float* __restrict__ b_ih, float* __restrict__ P) {
  __shared__ float emb[EE];
  int c = blockIdx.x;
  int tid = threadIdx.x;
  if (tid < EE) emb[tid] = char_emb[c * EE + tid];
  __syncthreads();
  for (int j = tid; j < 3 * HH; j += 256) {
    const float* wr = w_ih + (size_t)j * (NC + EE) + NC;
    float s = 0.f;
    for (int k = 0; k < EE; ++k) s += emb[k] * wr[k];
    P[(size_t)c * 1536 + j] = s + b_ih[j];
  }
}

__global__ __launch_bounds__(256) void build_wcat(
    const float* __restrict__ w_h2h, const float* __restrict__ w_hh,
    const float* __restrict__ b_h2h, const float* __restrict__ b_hh,
    float* __restrict__ Wcat, float* __restrict__ bcat) {
  int idx = blockIdx.x * 256 + threadIdx.x;  // float4 index, 2048*512/4 total
  const int n1 = 512 * 512 / 4;
  float4* dst = (float4*)Wcat;
  if (idx < n1)
    dst[idx] = ((const float4*)w_h2h)[idx];
  else
    dst[idx] = ((const float4*)w_hh)[idx - n1];
  if (idx < 2048) bcat[idx] = (idx < 512) ? b_h2h[idx] : b_hh[idx - 512];
}

__global__ __launch_bounds__(1024) void scan_tl(const int* __restrict__ tl,
                                                int* __restrict__ offs) {
  __shared__ int s[NB];
  int t = threadIdx.x;
  s[t] = tl[t];
  __syncthreads();
  for (int d = 1; d < NB; d <<= 1) {
    int v = (t >= d) ? s[t - d] : 0;
    __syncthreads();
    s[t] += v;
    __syncthreads();
  }
  offs[t] = s[t] - tl[t];
}

__global__ __launch_bounds__(256) void init_kernel(float* __restrict__ h0,
                                                   int* __restrict__ tgt) {
  int idx = blockIdx.x * 256 + threadIdx.x;
  if (idx < NB * HH) h0[idx] = 0.f;
  if (idx < NB) tgt[idx] = 0;
}

extern "C" void kernel_launch(void* const* d_in, const int* in_sizes, int n_in,
                              void* d_out, int out_size, void* d_ws,
                              size_t ws_size, hipStream_t stream) {
  const float* feats = (const float*)d_in[0];
  const float* w_i2h = (const float*)d_in[1];
  const float* w_h2h = (const float*)d_in[2];
  const float* b_h2h = (const float*)d_in[3];
  const float* w_score = (const float*)d_in[4];
  const float* w_ih = (const float*)d_in[5];
  const float* w_hh = (const float*)d_in[6];
  const float* b_ih = (const float*)d_in[7];
  const float* b_hh = (const float*)d_in[8];
  const float* char_emb = (const float*)d_in[9];
  const float* w_gen = (const float*)d_in[10];
  const float* b_gen = (const float*)d_in[11];
  const int* tl = (const int*)d_in[12];
  float* out = (float*)d_out;

  char* ws = (char*)d_ws;
  float* fp = (float*)ws;      ws += (size_t)NT * NB * HH * 4;  // 134 MB
  float* C1a = (float*)ws;     ws += (size_t)NB * 2048 * 4;
  float* C1b = (float*)ws;     ws += (size_t)NB * 2048 * 4;
  float* Ga = (float*)ws;      ws += (size_t)NB * 1536 * 4;
  float* Gb = (float*)ws;      ws += (size_t)NB * 1536 * 4;
  float* context = (float*)ws; ws += (size_t)NB * NC * 4;
  float* h0 = (float*)ws;      ws += (size_t)NB * HH * 4;
  float* h1 = (float*)ws;      ws += (size_t)NB * HH * 4;
  float* Wcat = (float*)ws;    ws += (size_t)2048 * 512 * 4;
  float* bcat = (float*)ws;    ws += 2048 * 4;
  float* P = (float*)ws;       ws += (size_t)98 * 1536 * 4;
  int* tgt = (int*)ws;         ws += 4096;
  int* offs = (int*)ws;        ws += 4096;

  hipLaunchKernelGGL(scan_tl, dim3(1), dim3(1024), 0, stream, tl, offs);
  hipLaunchKernelGGL(init_kernel, dim3((NB * HH) / 256), dim3(256), 0, stream,
                     h0, tgt);
  hipLaunchKernelGGL(build_wcat, dim3(1024), dim3(256), 0, stream, w_h2h, w_hh,
                     b_h2h, b_hh, Wcat, bcat);
  hipLaunchKernelGGL(build_P, dim3(98), dim3(256), 0, stream, char_emb, w_ih,
                     b_ih, P);
  // fp = feats @ w_i2h^T  [65536, 512]
  hipLaunchKernelGGL(gemm_bt_big, dim3(HH / 256, (NT * NB) / 128), dim3(256),
                     0, stream, feats, w_i2h, fp, NT * NB, HH, NC);

  // persistent cooperative step loop: 512 blocks x 256 thr (2 blocks/CU)
  void* kargs[] = {(void*)&fp,      (void*)&C1a,   (void*)&C1b,
                   (void*)&Ga,      (void*)&Gb,    (void*)&context,
                   (void*)&h0,      (void*)&h1,    (void*)&Wcat,
                   (void*)&bcat,    (void*)&P,     (void*)&w_ih,
                   (void*)&w_score, (void*)&feats, (void*)&w_gen,
                   (void*)&b_gen,   (void*)&tl,    (void*)&offs,
                   (void*)&out,     (void*)&tgt};
  hipError_t cerr = hipLaunchCooperativeKernel(
      reinterpret_cast<void*>(step_loop), dim3(512), dim3(256), kargs, 0,
      stream);
  if (cerr != hipSuccess) {
    // deterministic fallback: R5-verified multi-kernel loop (same math)
    float* hbuf[2] = {h0, h1};
    for (int s = 0; s < STEPS; ++s) {
      float* hc = hbuf[s & 1];
      float* hn = hbuf[(s + 1) & 1];
      hipLaunchKernelGGL(gemm_bt_ks, dim3(2048 / 128, NB / 64, 2), dim3(256),
                         0, stream, hc, HH, Wcat, 512, bcat, C1a, C1b, 2048);
      hipLaunchKernelGGL(step_attn2, dim3(NB), dim3(512), 0, stream, fp, C1a,
                         C1b, w_score, feats, context);
      hipLaunchKernelGGL(gemm_bt_ks, dim3(1536 / 128, NB / 64, 2), dim3(256),
                         0, stream, context, NC, w_ih, NC + EE,
                         (const float*)nullptr, Ga, Gb, 1536);
      hipLaunchKernelGGL(step_update2, dim3(NB), dim3(128), 0, stream, C1a,
                         C1b, Ga, Gb, P, hc, hn, w_gen, b_gen, tl, offs, out,
                         tgt, s);
    }
  }
}

// Round 8
// 4350.237 us; speedup vs baseline: 5.0628x; 5.0628x over previous
//
#include <hip/hip_runtime.h>
#include <math.h>

#define NT 64
#define NB 1024
#define NC 512
#define HH 512
#define EE 128
#define NCLS 97
#define STEPS 32

__device__ __forceinline__ float fast_tanh(float x) {
  float e = __expf(2.f * x);
  return 1.f - 2.f / (e + 1.f);
}
__device__ __forceinline__ float fast_sig(float x) {
  return 1.f / (1.f + __expf(-x));
}

// ---------------- big GEMM: C[M,N] = A[M,K] @ B[N,K]^T
// 128(M)x256(N) tile, 8x16 micro, split fragments (2-way-max LDS banks)
__global__ __launch_bounds__(256) void gemm_bt_big(
    const float* __restrict__ A, const float* __restrict__ B,
    float* __restrict__ C, int M, int N, int K) {
  __shared__ float As[16][132];
  __shared__ float Bs[16][260];
  const int bm = blockIdx.y * 128;
  const int bn = blockIdx.x * 256;
  const int tid = threadIdx.x;
  const int tx = tid & 15, ty = tid >> 4;
  const int sr = tid >> 1;       // 0..127
  const int sk = (tid & 1) * 8;  // 0 or 8
  float acc[8][16];
#pragma unroll
  for (int i = 0; i < 8; ++i)
#pragma unroll
    for (int j = 0; j < 16; ++j) acc[i][j] = 0.f;
  const float* Ap = A + (size_t)(bm + sr) * K + sk;
  const float* Bp0 = B + (size_t)(bn + sr) * K + sk;
  const float* Bp1 = B + (size_t)(bn + 128 + sr) * K + sk;
  for (int k0 = 0; k0 < K; k0 += 16) {
    float4 a0 = *(const float4*)(Ap + k0);
    float4 a1 = *(const float4*)(Ap + k0 + 4);
    float4 b00 = *(const float4*)(Bp0 + k0);
    float4 b01 = *(const float4*)(Bp0 + k0 + 4);
    float4 b10 = *(const float4*)(Bp1 + k0);
    float4 b11 = *(const float4*)(Bp1 + k0 + 4);
    As[sk + 0][sr] = a0.x; As[sk + 1][sr] = a0.y;
    As[sk + 2][sr] = a0.z; As[sk + 3][sr] = a0.w;
    As[sk + 4][sr] = a1.x; As[sk + 5][sr] = a1.y;
    As[sk + 6][sr] = a1.z; As[sk + 7][sr] = a1.w;
    Bs[sk + 0][sr] = b00.x; Bs[sk + 1][sr] = b00.y;
    Bs[sk + 2][sr] = b00.z; Bs[sk + 3][sr] = b00.w;
    Bs[sk + 4][sr] = b01.x; Bs[sk + 5][sr] = b01.y;
    Bs[sk + 6][sr] = b01.z; Bs[sk + 7][sr] = b01.w;
    Bs[sk + 0][128 + sr] = b10.x; Bs[sk + 1][128 + sr] = b10.y;
    Bs[sk + 2][128 + sr] = b10.z; Bs[sk + 3][128 + sr] = b10.w;
    Bs[sk + 4][128 + sr] = b11.x; Bs[sk + 5][128 + sr] = b11.y;
    Bs[sk + 6][128 + sr] = b11.z; Bs[sk + 7][128 + sr] = b11.w;
    __syncthreads();
#pragma unroll
    for (int kk = 0; kk < 16; ++kk) {
      float a[8], b[16];
      *(float4*)&a[0] = *(const float4*)&As[kk][ty * 4];
      *(float4*)&a[4] = *(const float4*)&As[kk][64 + ty * 4];
      *(float4*)&b[0] = *(const float4*)&Bs[kk][tx * 4];
      *(float4*)&b[4] = *(const float4*)&Bs[kk][64 + tx * 4];
      *(float4*)&b[8] = *(const float4*)&Bs[kk][128 + tx * 4];
      *(float4*)&b[12] = *(const float4*)&Bs[kk][192 + tx * 4];
#pragma unroll
      for (int i = 0; i < 8; ++i)
#pragma unroll
        for (int j = 0; j < 16; ++j) acc[i][j] += a[i] * b[j];
    }
    __syncthreads();
  }
#pragma unroll
  for (int ig = 0; ig < 2; ++ig)
#pragma unroll
    for (int i = 0; i < 4; ++i) {
      int row = bm + ig * 64 + ty * 4 + i;
      int ai = ig * 4 + i;
#pragma unroll
      for (int jg = 0; jg < 4; ++jg) {
        float4 o;
        o.x = acc[ai][jg * 4 + 0];
        o.y = acc[ai][jg * 4 + 1];
        o.z = acc[ai][jg * 4 + 2];
        o.w = acc[ai][jg * 4 + 3];
        *(float4*)(C + (size_t)row * N + bn + jg * 64 + tx * 4) = o;
      }
    }
}

// ---------------- step GEMM, K=512 split in 2 halves (blockIdx.z), with
// active-row limit: tiles fully beyond cnt[step] rows exit immediately.
// 64(M)x128(N) tile, BK=16, 4x8 micro split-col. Consumers add the halves.
__global__ __launch_bounds__(256) void gemm_bt_ks(
    const float* __restrict__ A, int lda, const float* __restrict__ B, int ldb,
    const float* __restrict__ bias, float* __restrict__ Ca,
    float* __restrict__ Cb, int ldc, const int* __restrict__ cnt, int step) {
  const int bm = blockIdx.y * 64;
  if (bm >= cnt[step]) return;
  __shared__ float As[16][66];
  __shared__ float Bs[16][132];
  const int kh = blockIdx.z;
  const int kbase = kh * 256;
  float* __restrict__ C = kh ? Cb : Ca;
  const int bn = blockIdx.x * 128;
  const int tid = threadIdx.x;
  const int tx = tid & 15, ty = tid >> 4;
  const int ar = tid >> 2, ak = (tid & 3) * 4;
  const int br = tid >> 1, bk = (tid & 1) * 8;
  float acc[4][8];
#pragma unroll
  for (int i = 0; i < 4; ++i)
#pragma unroll
    for (int j = 0; j < 8; ++j) acc[i][j] = 0.f;
  const float* Ap = A + (size_t)(bm + ar) * lda + kbase + ak;
  const float* Bp = B + (size_t)(bn + br) * ldb + kbase + bk;
  for (int k0 = 0; k0 < 256; k0 += 16) {
    float4 av = *(const float4*)(Ap + k0);
    float4 b0 = *(const float4*)(Bp + k0);
    float4 b1 = *(const float4*)(Bp + k0 + 4);
    As[ak + 0][ar] = av.x; As[ak + 1][ar] = av.y;
    As[ak + 2][ar] = av.z; As[ak + 3][ar] = av.w;
    Bs[bk + 0][br] = b0.x; Bs[bk + 1][br] = b0.y;
    Bs[bk + 2][br] = b0.z; Bs[bk + 3][br] = b0.w;
    Bs[bk + 4][br] = b1.x; Bs[bk + 5][br] = b1.y;
    Bs[bk + 6][br] = b1.z; Bs[bk + 7][br] = b1.w;
    __syncthreads();
#pragma unroll
    for (int kk = 0; kk < 16; ++kk) {
      float a[4], b[8];
      *(float4*)&a[0] = *(const float4*)&As[kk][ty * 4];
      *(float4*)&b[0] = *(const float4*)&Bs[kk][tx * 4];
      *(float4*)&b[4] = *(const float4*)&Bs[kk][64 + tx * 4];
#pragma unroll
      for (int i = 0; i < 4; ++i)
#pragma unroll
        for (int j = 0; j < 8; ++j) acc[i][j] += a[i] * b[j];
    }
    __syncthreads();
  }
  float bc0[4] = {0.f, 0.f, 0.f, 0.f};
  float bc1[4] = {0.f, 0.f, 0.f, 0.f};
  if (bias && kh == 0) {
    *(float4*)bc0 = *(const float4*)(bias + bn + tx * 4);
    *(float4*)bc1 = *(const float4*)(bias + bn + 64 + tx * 4);
  }
#pragma unroll
  for (int i = 0; i < 4; ++i) {
    int row = bm + ty * 4 + i;
    float4 o0, o1;
    o0.x = acc[i][0] + bc0[0]; o0.y = acc[i][1] + bc0[1];
    o0.z = acc[i][2] + bc0[2]; o0.w = acc[i][3] + bc0[3];
    o1.x = acc[i][4] + bc1[0]; o1.y = acc[i][5] + bc1[1];
    o1.z = acc[i][6] + bc1[2]; o1.w = acc[i][7] + bc1[3];
    *(float4*)(C + (size_t)row * ldc + bn + tx * 4) = o0;
    *(float4*)(C + (size_t)row * ldc + bn + 64 + tx * 4) = o1;
  }
}

// ---------------- fused e + softmax + context; block i = compacted index
__global__ __launch_bounds__(512) void step_attn2(
    const float* __restrict__ fp, const float* __restrict__ C1a,
    const float* __restrict__ C1b, const float* __restrict__ w_score,
    const float* __restrict__ feats, float* __restrict__ context,
    const int* __restrict__ perm, const int* __restrict__ cnt, int step) {
  const int i0 = blockIdx.x;
  if (i0 >= cnt[step]) return;
  __shared__ float es[NT];
  __shared__ float als[NT];
  const int b = perm[i0];
  const int tid = threadIdx.x;
  const int lane = tid & 63, wid = tid >> 6;
  const float* hpa = C1a + (size_t)i0 * 2048 + lane * 8;
  const float* hpb = C1b + (size_t)i0 * 2048 + lane * 8;
  float4 ha0 = *(const float4*)hpa;
  float4 ha1 = *(const float4*)(hpa + 4);
  float4 hb0 = *(const float4*)hpb;
  float4 hb1 = *(const float4*)(hpb + 4);
  float4 h0, h1;
  h0.x = ha0.x + hb0.x; h0.y = ha0.y + hb0.y;
  h0.z = ha0.z + hb0.z; h0.w = ha0.w + hb0.w;
  h1.x = ha1.x + hb1.x; h1.y = ha1.y + hb1.y;
  h1.z = ha1.z + hb1.z; h1.w = ha1.w + hb1.w;
  float4 w0 = *(const float4*)(w_score + lane * 8);
  float4 w1 = *(const float4*)(w_score + lane * 8 + 4);
#pragma unroll
  for (int pass = 0; pass < 2; ++pass) {
    float4 f0[4], f1[4];
#pragma unroll
    for (int i = 0; i < 4; ++i) {
      int t = wid * 8 + pass * 4 + i;
      const float* fr = fp + ((size_t)t * NB + b) * HH + lane * 8;
      f0[i] = *(const float4*)fr;
      f1[i] = *(const float4*)(fr + 4);
    }
#pragma unroll
    for (int i = 0; i < 4; ++i) {
      float acc = 0.f;
      acc += fast_tanh(f0[i].x + h0.x) * w0.x;
      acc += fast_tanh(f0[i].y + h0.y) * w0.y;
      acc += fast_tanh(f0[i].z + h0.z) * w0.z;
      acc += fast_tanh(f0[i].w + h0.w) * w0.w;
      acc += fast_tanh(f1[i].x + h1.x) * w1.x;
      acc += fast_tanh(f1[i].y + h1.y) * w1.y;
      acc += fast_tanh(f1[i].z + h1.z) * w1.z;
      acc += fast_tanh(f1[i].w + h1.w) * w1.w;
#pragma unroll
      for (int off = 32; off > 0; off >>= 1) acc += __shfl_down(acc, off, 64);
      if (lane == 0) es[wid * 8 + pass * 4 + i] = acc;
    }
  }
  __syncthreads();
  if (tid < 64) {
    float v = es[tid];
    float mx = v;
#pragma unroll
    for (int off = 32; off > 0; off >>= 1) mx = fmaxf(mx, __shfl_xor(mx, off, 64));
    float p = __expf(v - mx);
    float sum = p;
#pragma unroll
    for (int off = 32; off > 0; off >>= 1) sum += __shfl_xor(sum, off, 64);
    als[tid] = p / sum;
  }
  __syncthreads();
  float a0 = 0.f, a1 = 0.f, a2 = 0.f, a3 = 0.f;
  const float* fb = feats + (size_t)b * NC + tid;
#pragma unroll 4
  for (int t = 0; t < NT; t += 4) {
    a0 += als[t + 0] * fb[(size_t)(t + 0) * NB * NC];
    a1 += als[t + 1] * fb[(size_t)(t + 1) * NB * NC];
    a2 += als[t + 2] * fb[(size_t)(t + 2) * NB * NC];
    a3 += als[t + 3] * fb[(size_t)(t + 3) * NB * NC];
  }
  context[(size_t)i0 * NC + tid] = ((a0 + a1) + (a2 + a3));
}

// ---------------- fused GRU gates + logits + argmax; block i = compacted idx
__global__ __launch_bounds__(128) void step_update2(
    const float* __restrict__ C1a, const float* __restrict__ C1b,
    const float* __restrict__ Ga, const float* __restrict__ Gb,
    const float* __restrict__ P, const float* __restrict__ hc,
    float* __restrict__ hn_out, const float* __restrict__ w_gen,
    const float* __restrict__ b_gen, const int* __restrict__ offs,
    float* __restrict__ out, int* __restrict__ tgt,
    const int* __restrict__ perm, const int* __restrict__ cnt, int step) {
  const int i0 = blockIdx.x;
  if (i0 >= cnt[step]) return;
  __shared__ float hs[HH];
  __shared__ float lv[128];
  __shared__ int li[128];
  const int b = perm[i0];
  const int tid = threadIdx.x;
  const int tg = tgt[b];
  const float* gia = Ga + (size_t)i0 * 1536;
  const float* gib = Gb + (size_t)i0 * 1536;
  const float* Pb = P + (size_t)tg * 1536;
  const float* gha = C1a + (size_t)i0 * 2048 + 512;
  const float* ghb = C1b + (size_t)i0 * 2048 + 512;
#pragma unroll
  for (int i = 0; i < 4; ++i) {
    int j = tid + i * 128;
    float ir = gia[j] + gib[j] + Pb[j];
    float iz = gia[512 + j] + gib[512 + j] + Pb[512 + j];
    float in = gia[1024 + j] + gib[1024 + j] + Pb[1024 + j];
    float hr = gha[j] + ghb[j];
    float hz = gha[512 + j] + ghb[512 + j];
    float hnv = gha[1024 + j] + ghb[1024 + j];
    float r = fast_sig(ir + hr);
    float z = fast_sig(iz + hz);
    float n = fast_tanh(in + r * hnv);
    float h = hc[(size_t)i0 * HH + j];
    float hv = (1.f - z) * n + z * h;
    hs[j] = hv;
    hn_out[(size_t)i0 * HH + j] = hv;
  }
  __syncthreads();
  float acc = -INFINITY;
  if (tid < NCLS) {
    const float4* wr4 = (const float4*)(w_gen + (size_t)tid * HH);
    float s = 0.f;
    for (int k = 0; k < HH / 4; ++k) {
      float4 w = wr4[k];
      s += hs[4 * k + 0] * w.x + hs[4 * k + 1] * w.y +
           hs[4 * k + 2] * w.z + hs[4 * k + 3] * w.w;
    }
    acc = s + b_gen[tid];
    out[(size_t)(offs[b] + step) * NCLS + tid] = acc;  // active => step < tl[b]
  }
  lv[tid] = acc;
  li[tid] = tid;
  __syncthreads();
  for (int d = 64; d > 0; d >>= 1) {
    if (tid < d) {
      float v2 = lv[tid + d];
      int i2 = li[tid + d];
      if (v2 > lv[tid] || (v2 == lv[tid] && i2 < li[tid])) {
        lv[tid] = v2;
        li[tid] = i2;
      }
    }
    __syncthreads();
  }
  if (tid == 0) tgt[b] = li[0] + 1;
}

// ---------------- one-time setup kernels
// perm = batches sorted by tl desc (stable); cnt[s] = #{b: tl[b] > s};
// offs = exclusive prefix sum of tl (original order)
__global__ __launch_bounds__(1024) void sort_tl(const int* __restrict__ tl,
                                                int* __restrict__ perm,
                                                int* __restrict__ cnt,
                                                int* __restrict__ offs) {
  __shared__ int s[NB];
  const int t = threadIdx.x;
  s[t] = tl[t];
  __syncthreads();
  const int myv = s[t];
  int pos = 0;
  int pre = 0;
  for (int b = 0; b < NB; ++b) {
    int v = s[b];
    pos += (v > myv || (v == myv && b < t)) ? 1 : 0;
    pre += (b < t) ? v : 0;
  }
  perm[pos] = t;
  offs[t] = pre;
  if (t < STEPS) {
    int c = 0;
    for (int b = 0; b < NB; ++b) c += (s[b] > t) ? 1 : 0;
    cnt[t] = c;
  }
}

__global__ __launch_bounds__(256) void build_P(
    const float* __restrict__ char_emb, const float* __restrict__ w_ih,
    const float* __restrict__ b_ih, float* __restrict__ P) {
  __shared__ float emb[EE];
  int c = blockIdx.x;
  int tid = threadIdx.x;
  if (tid < EE) emb[tid] = char_emb[c * EE + tid];
  __syncthreads();
  for (int j = tid; j < 3 * HH; j += 256) {
    const float* wr = w_ih + (size_t)j * (NC + EE) + NC;
    float s = 0.f;
    for (int k = 0; k < EE; ++k) s += emb[k] * wr[k];
    P[(size_t)c * 1536 + j] = s + b_ih[j];
  }
}

__global__ __launch_bounds__(256) void build_wcat(
    const float* __restrict__ w_h2h, const float* __restrict__ w_hh,
    const float* __restrict__ b_h2h, const float* __restrict__ b_hh,
    float* __restrict__ Wcat, float* __restrict__ bcat) {
  int idx = blockIdx.x * 256 + threadIdx.x;  // float4 index, 2048*512/4 total
  const int n1 = 512 * 512 / 4;
  float4* dst = (float4*)Wcat;
  if (idx < n1)
    dst[idx] = ((const float4*)w_h2h)[idx];
  else
    dst[idx] = ((const float4*)w_hh)[idx - n1];
  if (idx < 2048) bcat[idx] = (idx < 512) ? b_h2h[idx] : b_hh[idx - 512];
}

__global__ __launch_bounds__(256) void init_kernel(float* __restrict__ h0,
                                                   int* __restrict__ tgt) {
  int idx = blockIdx.x * 256 + threadIdx.x;
  if (idx < NB * HH) h0[idx] = 0.f;
  if (idx < NB) tgt[idx] = 0;
}

extern "C" void kernel_launch(void* const* d_in, const int* in_sizes, int n_in,
                              void* d_out, int out_size, void* d_ws,
                              size_t ws_size, hipStream_t stream) {
  const float* feats = (const float*)d_in[0];
  const float* w_i2h = (const float*)d_in[1];
  const float* w_h2h = (const float*)d_in[2];
  const float* b_h2h = (const float*)d_in[3];
  const float* w_score = (const float*)d_in[4];
  const float* w_ih = (const float*)d_in[5];
  const float* w_hh = (const float*)d_in[6];
  const float* b_ih = (const float*)d_in[7];
  const float* b_hh = (const float*)d_in[8];
  const float* char_emb = (const float*)d_in[9];
  const float* w_gen = (const float*)d_in[10];
  const float* b_gen = (const float*)d_in[11];
  const int* tl = (const int*)d_in[12];
  float* out = (float*)d_out;

  char* ws = (char*)d_ws;
  float* fp = (float*)ws;      ws += (size_t)NT * NB * HH * 4;  // 134 MB
  float* C1a = (float*)ws;     ws += (size_t)NB * 2048 * 4;
  float* C1b = (float*)ws;     ws += (size_t)NB * 2048 * 4;
  float* Ga = (float*)ws;      ws += (size_t)NB * 1536 * 4;
  float* Gb = (float*)ws;      ws += (size_t)NB * 1536 * 4;
  float* context = (float*)ws; ws += (size_t)NB * NC * 4;
  float* h0 = (float*)ws;      ws += (size_t)NB * HH * 4;
  float* h1 = (float*)ws;      ws += (size_t)NB * HH * 4;
  float* Wcat = (float*)ws;    ws += (size_t)2048 * 512 * 4;
  float* bcat = (float*)ws;    ws += 2048 * 4;
  float* P = (float*)ws;       ws += (size_t)98 * 1536 * 4;
  int* tgt = (int*)ws;         ws += 4096;
  int* offs = (int*)ws;        ws += 4096;
  int* perm = (int*)ws;        ws += 4096;
  int* cnt = (int*)ws;         ws += 4096;

  hipLaunchKernelGGL(sort_tl, dim3(1), dim3(1024), 0, stream, tl, perm, cnt,
                     offs);
  hipLaunchKernelGGL(init_kernel, dim3((NB * HH) / 256), dim3(256), 0, stream,
                     h0, tgt);
  hipLaunchKernelGGL(build_wcat, dim3(1024), dim3(256), 0, stream, w_h2h, w_hh,
                     b_h2h, b_hh, Wcat, bcat);
  hipLaunchKernelGGL(build_P, dim3(98), dim3(256), 0, stream, char_emb, w_ih,
                     b_ih, P);
  // fp = feats @ w_i2h^T  [65536, 512]
  hipLaunchKernelGGL(gemm_bt_big, dim3(HH / 256, (NT * NB) / 128), dim3(256),
                     0, stream, feats, w_i2h, fp, NT * NB, HH, NC);

  float* hbuf[2] = {h0, h1};
  for (int s = 0; s < STEPS; ++s) {
    float* hc = hbuf[s & 1];
    float* hn = hbuf[(s + 1) & 1];
    // C1 = hcomp @ Wcat^T + bcat   [cnt(s),2048], K-split-2
    hipLaunchKernelGGL(gemm_bt_ks, dim3(2048 / 128, NB / 64, 2), dim3(256), 0,
                       stream, hc, HH, Wcat, 512, bcat, C1a, C1b, 2048, cnt,
                       s);
    hipLaunchKernelGGL(step_attn2, dim3(NB), dim3(512), 0, stream, fp, C1a,
                       C1b, w_score, feats, context, perm, cnt, s);
    // gi = context @ w_ih[:, :512]^T   [cnt(s),1536], K-split-2
    hipLaunchKernelGGL(gemm_bt_ks, dim3(1536 / 128, NB / 64, 2), dim3(256), 0,
                       stream, context, NC, w_ih, NC + EE,
                       (const float*)nullptr, Ga, Gb, 1536, cnt, s);
    hipLaunchKernelGGL(step_update2, dim3(NB), dim3(128), 0, stream, C1a, C1b,
                       Ga, Gb, P, hc, hn, w_gen, b_gen, offs, out, tgt, perm,
                       cnt, s);
  }
}

// Round 9
// 4022.213 us; speedup vs baseline: 5.4757x; 1.0816x over previous
//
#include <hip/hip_runtime.h>
#include <math.h>

#define NT 64
#define NB 1024
#define NC 512
#define HH 512
#define EE 128
#define NCLS 97
#define STEPS 32

__device__ __forceinline__ float fast_tanh(float x) {
  float e = __expf(2.f * x);
  return 1.f - 2.f / (e + 1.f);
}
__device__ __forceinline__ float fast_sig(float x) {
  return 1.f / (1.f + __expf(-x));
}

// ---------------- big GEMM: C[M,N] = A[M,K] @ B[N,K]^T, 128x128 tile,
// 8x8 micro (split fragments, 2-way-max banks) + register-prefetch dbuf
__global__ __launch_bounds__(256) void gemm_bt_128p(
    const float* __restrict__ A, const float* __restrict__ B,
    float* __restrict__ C, int M, int N, int K) {
  __shared__ float As[16][132];
  __shared__ float Bs[16][132];
  const int bm = blockIdx.y * 128;
  const int bn = blockIdx.x * 128;
  const int tid = threadIdx.x;
  const int tx = tid & 15, ty = tid >> 4;
  const int sr = tid >> 1;       // 0..127
  const int sk = (tid & 1) * 8;  // 0 or 8
  float acc[8][8];
#pragma unroll
  for (int i = 0; i < 8; ++i)
#pragma unroll
    for (int j = 0; j < 8; ++j) acc[i][j] = 0.f;
  const float* Ap = A + (size_t)(bm + sr) * K + sk;
  const float* Bp = B + (size_t)(bn + sr) * K + sk;
  float4 pa0 = *(const float4*)(Ap);
  float4 pa1 = *(const float4*)(Ap + 4);
  float4 pb0 = *(const float4*)(Bp);
  float4 pb1 = *(const float4*)(Bp + 4);
  for (int k0 = 0; k0 < K; k0 += 16) {
    As[sk + 0][sr] = pa0.x; As[sk + 1][sr] = pa0.y;
    As[sk + 2][sr] = pa0.z; As[sk + 3][sr] = pa0.w;
    As[sk + 4][sr] = pa1.x; As[sk + 5][sr] = pa1.y;
    As[sk + 6][sr] = pa1.z; As[sk + 7][sr] = pa1.w;
    Bs[sk + 0][sr] = pb0.x; Bs[sk + 1][sr] = pb0.y;
    Bs[sk + 2][sr] = pb0.z; Bs[sk + 3][sr] = pb0.w;
    Bs[sk + 4][sr] = pb1.x; Bs[sk + 5][sr] = pb1.y;
    Bs[sk + 6][sr] = pb1.z; Bs[sk + 7][sr] = pb1.w;
    __syncthreads();
    if (k0 + 16 < K) {
      pa0 = *(const float4*)(Ap + k0 + 16);
      pa1 = *(const float4*)(Ap + k0 + 20);
      pb0 = *(const float4*)(Bp + k0 + 16);
      pb1 = *(const float4*)(Bp + k0 + 20);
    }
#pragma unroll
    for (int kk = 0; kk < 16; ++kk) {
      float a[8], b[8];
      *(float4*)&a[0] = *(const float4*)&As[kk][ty * 4];
      *(float4*)&a[4] = *(const float4*)&As[kk][64 + ty * 4];
      *(float4*)&b[0] = *(const float4*)&Bs[kk][tx * 4];
      *(float4*)&b[4] = *(const float4*)&Bs[kk][64 + tx * 4];
#pragma unroll
      for (int i = 0; i < 8; ++i)
#pragma unroll
        for (int j = 0; j < 8; ++j) acc[i][j] += a[i] * b[j];
    }
    __syncthreads();
  }
#pragma unroll
  for (int ig = 0; ig < 2; ++ig)
#pragma unroll
    for (int i = 0; i < 4; ++i) {
      int row = bm + ig * 64 + ty * 4 + i;
      float4 o0, o1;
      o0.x = acc[ig * 4 + i][0]; o0.y = acc[ig * 4 + i][1];
      o0.z = acc[ig * 4 + i][2]; o0.w = acc[ig * 4 + i][3];
      o1.x = acc[ig * 4 + i][4]; o1.y = acc[ig * 4 + i][5];
      o1.z = acc[ig * 4 + i][6]; o1.w = acc[ig * 4 + i][7];
      *(float4*)(C + (size_t)row * N + bn + tx * 4) = o0;
      *(float4*)(C + (size_t)row * N + bn + 64 + tx * 4) = o1;
    }
}

// ---------------- step GEMM, K=512 split in 2 halves (blockIdx.z), with
// active-row gating + register-prefetch dbuf. 64x128 tile, 4x8 micro.
__global__ __launch_bounds__(256) void gemm_bt_ks(
    const float* __restrict__ A, int lda, const float* __restrict__ B, int ldb,
    const float* __restrict__ bias, float* __restrict__ Ca,
    float* __restrict__ Cb, int ldc, const int* __restrict__ cnt, int step) {
  const int bm = blockIdx.y * 64;
  if (bm >= cnt[step]) return;
  __shared__ float As[16][66];
  __shared__ float Bs[16][132];
  const int kh = blockIdx.z;
  const int kbase = kh * 256;
  float* __restrict__ C = kh ? Cb : Ca;
  const int bn = blockIdx.x * 128;
  const int tid = threadIdx.x;
  const int tx = tid & 15, ty = tid >> 4;
  const int ar = tid >> 2, ak = (tid & 3) * 4;
  const int br = tid >> 1, bk = (tid & 1) * 8;
  float acc[4][8];
#pragma unroll
  for (int i = 0; i < 4; ++i)
#pragma unroll
    for (int j = 0; j < 8; ++j) acc[i][j] = 0.f;
  const float* Ap = A + (size_t)(bm + ar) * lda + kbase + ak;
  const float* Bp = B + (size_t)(bn + br) * ldb + kbase + bk;
  float4 pav = *(const float4*)(Ap);
  float4 pb0 = *(const float4*)(Bp);
  float4 pb1 = *(const float4*)(Bp + 4);
  for (int k0 = 0; k0 < 256; k0 += 16) {
    As[ak + 0][ar] = pav.x; As[ak + 1][ar] = pav.y;
    As[ak + 2][ar] = pav.z; As[ak + 3][ar] = pav.w;
    Bs[bk + 0][br] = pb0.x; Bs[bk + 1][br] = pb0.y;
    Bs[bk + 2][br] = pb0.z; Bs[bk + 3][br] = pb0.w;
    Bs[bk + 4][br] = pb1.x; Bs[bk + 5][br] = pb1.y;
    Bs[bk + 6][br] = pb1.z; Bs[bk + 7][br] = pb1.w;
    __syncthreads();
    if (k0 + 16 < 256) {
      pav = *(const float4*)(Ap + k0 + 16);
      pb0 = *(const float4*)(Bp + k0 + 16);
      pb1 = *(const float4*)(Bp + k0 + 20);
    }
#pragma unroll
    for (int kk = 0; kk < 16; ++kk) {
      float a[4], b[8];
      *(float4*)&a[0] = *(const float4*)&As[kk][ty * 4];
      *(float4*)&b[0] = *(const float4*)&Bs[kk][tx * 4];
      *(float4*)&b[4] = *(const float4*)&Bs[kk][64 + tx * 4];
#pragma unroll
      for (int i = 0; i < 4; ++i)
#pragma unroll
        for (int j = 0; j < 8; ++j) acc[i][j] += a[i] * b[j];
    }
    __syncthreads();
  }
  float bc0[4] = {0.f, 0.f, 0.f, 0.f};
  float bc1[4] = {0.f, 0.f, 0.f, 0.f};
  if (bias && kh == 0) {
    *(float4*)bc0 = *(const float4*)(bias + bn + tx * 4);
    *(float4*)bc1 = *(const float4*)(bias + bn + 64 + tx * 4);
  }
#pragma unroll
  for (int i = 0; i < 4; ++i) {
    int row = bm + ty * 4 + i;
    float4 o0, o1;
    o0.x = acc[i][0] + bc0[0]; o0.y = acc[i][1] + bc0[1];
    o0.z = acc[i][2] + bc0[2]; o0.w = acc[i][3] + bc0[3];
    o1.x = acc[i][4] + bc1[0]; o1.y = acc[i][5] + bc1[1];
    o1.z = acc[i][6] + bc1[2]; o1.w = acc[i][7] + bc1[3];
    *(float4*)(C + (size_t)row * ldc + bn + tx * 4) = o0;
    *(float4*)(C + (size_t)row * ldc + bn + 64 + tx * 4) = o1;
  }
}

// ---------------- fused e + softmax + context; block i = compacted index
__global__ __launch_bounds__(512) void step_attn2(
    const float* __restrict__ fp, const float* __restrict__ C1a,
    const float* __restrict__ C1b, const float* __restrict__ w_score,
    const float* __restrict__ feats, float* __restrict__ context,
    const int* __restrict__ perm, const int* __restrict__ cnt, int step) {
  const int i0 = blockIdx.x;
  if (i0 >= cnt[step]) return;
  __shared__ float es[NT];
  __shared__ float als[NT];
  const int b = perm[i0];
  const int tid = threadIdx.x;
  const int lane = tid & 63, wid = tid >> 6;
  const float* hpa = C1a + (size_t)i0 * 2048 + lane * 8;
  const float* hpb = C1b + (size_t)i0 * 2048 + lane * 8;
  float4 ha0 = *(const float4*)hpa;
  float4 ha1 = *(const float4*)(hpa + 4);
  float4 hb0 = *(const float4*)hpb;
  float4 hb1 = *(const float4*)(hpb + 4);
  float4 h0, h1;
  h0.x = ha0.x + hb0.x; h0.y = ha0.y + hb0.y;
  h0.z = ha0.z + hb0.z; h0.w = ha0.w + hb0.w;
  h1.x = ha1.x + hb1.x; h1.y = ha1.y + hb1.y;
  h1.z = ha1.z + hb1.z; h1.w = ha1.w + hb1.w;
  float4 w0 = *(const float4*)(w_score + lane * 8);
  float4 w1 = *(const float4*)(w_score + lane * 8 + 4);
#pragma unroll
  for (int pass = 0; pass < 2; ++pass) {
    float4 f0[4], f1[4];
#pragma unroll
    for (int i = 0; i < 4; ++i) {
      int t = wid * 8 + pass * 4 + i;
      const float* fr = fp + ((size_t)t * NB + b) * HH + lane * 8;
      f0[i] = *(const float4*)fr;
      f1[i] = *(const float4*)(fr + 4);
    }
#pragma unroll
    for (int i = 0; i < 4; ++i) {
      float acc = 0.f;
      acc += fast_tanh(f0[i].x + h0.x) * w0.x;
      acc += fast_tanh(f0[i].y + h0.y) * w0.y;
      acc += fast_tanh(f0[i].z + h0.z) * w0.z;
      acc += fast_tanh(f0[i].w + h0.w) * w0.w;
      acc += fast_tanh(f1[i].x + h1.x) * w1.x;
      acc += fast_tanh(f1[i].y + h1.y) * w1.y;
      acc += fast_tanh(f1[i].z + h1.z) * w1.z;
      acc += fast_tanh(f1[i].w + h1.w) * w1.w;
#pragma unroll
      for (int off = 32; off > 0; off >>= 1) acc += __shfl_down(acc, off, 64);
      if (lane == 0) es[wid * 8 + pass * 4 + i] = acc;
    }
  }
  __syncthreads();
  if (tid < 64) {
    float v = es[tid];
    float mx = v;
#pragma unroll
    for (int off = 32; off > 0; off >>= 1) mx = fmaxf(mx, __shfl_xor(mx, off, 64));
    float p = __expf(v - mx);
    float sum = p;
#pragma unroll
    for (int off = 32; off > 0; off >>= 1) sum += __shfl_xor(sum, off, 64);
    als[tid] = p / sum;
  }
  __syncthreads();
  float a0 = 0.f, a1 = 0.f, a2 = 0.f, a3 = 0.f;
  const float* fb = feats + (size_t)b * NC + tid;
#pragma unroll 4
  for (int t = 0; t < NT; t += 4) {
    a0 += als[t + 0] * fb[(size_t)(t + 0) * NB * NC];
    a1 += als[t + 1] * fb[(size_t)(t + 1) * NB * NC];
    a2 += als[t + 2] * fb[(size_t)(t + 2) * NB * NC];
    a3 += als[t + 3] * fb[(size_t)(t + 3) * NB * NC];
  }
  context[(size_t)i0 * NC + tid] = ((a0 + a1) + (a2 + a3));
}

// ---------------- fused GRU gates + logits + argmax; block i = compacted idx
__global__ __launch_bounds__(128) void step_update2(
    const float* __restrict__ C1a, const float* __restrict__ C1b,
    const float* __restrict__ Ga, const float* __restrict__ Gb,
    const float* __restrict__ P, const float* __restrict__ hc,
    float* __restrict__ hn_out, const float* __restrict__ w_gen,
    const float* __restrict__ b_gen, const int* __restrict__ offs,
    float* __restrict__ out, int* __restrict__ tgt,
    const int* __restrict__ perm, const int* __restrict__ cnt, int step) {
  const int i0 = blockIdx.x;
  if (i0 >= cnt[step]) return;
  __shared__ float hs[HH];
  __shared__ float lv[128];
  __shared__ int li[128];
  const int b = perm[i0];
  const int tid = threadIdx.x;
  const int tg = tgt[b];
  const float* gia = Ga + (size_t)i0 * 1536;
  const float* gib = Gb + (size_t)i0 * 1536;
  const float* Pb = P + (size_t)tg * 1536;
  const float* gha = C1a + (size_t)i0 * 2048 + 512;
  const float* ghb = C1b + (size_t)i0 * 2048 + 512;
#pragma unroll
  for (int i = 0; i < 4; ++i) {
    int j = tid + i * 128;
    float ir = gia[j] + gib[j] + Pb[j];
    float iz = gia[512 + j] + gib[512 + j] + Pb[512 + j];
    float in = gia[1024 + j] + gib[1024 + j] + Pb[1024 + j];
    float hr = gha[j] + ghb[j];
    float hz = gha[512 + j] + ghb[512 + j];
    float hnv = gha[1024 + j] + ghb[1024 + j];
    float r = fast_sig(ir + hr);
    float z = fast_sig(iz + hz);
    float n = fast_tanh(in + r * hnv);
    float h = hc[(size_t)i0 * HH + j];
    float hv = (1.f - z) * n + z * h;
    hs[j] = hv;
    hn_out[(size_t)i0 * HH + j] = hv;
  }
  __syncthreads();
  float acc = -INFINITY;
  if (tid < NCLS) {
    const float4* wr4 = (const float4*)(w_gen + (size_t)tid * HH);
    float s = 0.f;
    for (int k = 0; k < HH / 4; ++k) {
      float4 w = wr4[k];
      s += hs[4 * k + 0] * w.x + hs[4 * k + 1] * w.y +
           hs[4 * k + 2] * w.z + hs[4 * k + 3] * w.w;
    }
    acc = s + b_gen[tid];
    out[(size_t)(offs[b] + step) * NCLS + tid] = acc;  // active => step < tl[b]
  }
  lv[tid] = acc;
  li[tid] = tid;
  __syncthreads();
  for (int d = 64; d > 0; d >>= 1) {
    if (tid < d) {
      float v2 = lv[tid + d];
      int i2 = li[tid + d];
      if (v2 > lv[tid] || (v2 == lv[tid] && i2 < li[tid])) {
        lv[tid] = v2;
        li[tid] = i2;
      }
    }
    __syncthreads();
  }
  if (tid == 0) tgt[b] = li[0] + 1;
}

// ---------------- one-time setup kernels
__global__ __launch_bounds__(1024) void sort_tl(const int* __restrict__ tl,
                                                int* __restrict__ perm,
                                                int* __restrict__ cnt,
                                                int* __restrict__ offs) {
  __shared__ int s[NB];
  const int t = threadIdx.x;
  s[t] = tl[t];
  __syncthreads();
  const int myv = s[t];
  int pos = 0;
  int pre = 0;
  for (int b = 0; b < NB; ++b) {
    int v = s[b];
    pos += (v > myv || (v == myv && b < t)) ? 1 : 0;
    pre += (b < t) ? v : 0;
  }
  perm[pos] = t;
  offs[t] = pre;
  if (t < STEPS) {
    int c = 0;
    for (int b = 0; b < NB; ++b) c += (s[b] > t) ? 1 : 0;
    cnt[t] = c;
  }
}

__global__ __launch_bounds__(256) void build_P(
    const float* __restrict__ char_emb, const float* __restrict__ w_ih,
    const float* __restrict__ b_ih, float* __restrict__ P) {
  __shared__ float emb[EE];
  int c = blockIdx.x;
  int tid = threadIdx.x;
  if (tid < EE) emb[tid] = char_emb[c * EE + tid];
  __syncthreads();
  for (int j = tid; j < 3 * HH; j += 256) {
    const float* wr = w_ih + (size_t)j * (NC + EE) + NC;
    float s = 0.f;
    for (int k = 0; k < EE; ++k) s += emb[k] * wr[k];
    P[(size_t)c * 1536 + j] = s + b_ih[j];
  }
}

__global__ __launch_bounds__(256) void build_wcat(
    const float* __restrict__ w_h2h, const float* __restrict__ w_hh,
    const float* __restrict__ b_h2h, const float* __restrict__ b_hh,
    float* __restrict__ Wcat, float* __restrict__ bcat) {
  int idx = blockIdx.x * 256 + threadIdx.x;  // float4 index, 2048*512/4 total
  const int n1 = 512 * 512 / 4;
  float4* dst = (float4*)Wcat;
  if (idx < n1)
    dst[idx] = ((const float4*)w_h2h)[idx];
  else
    dst[idx] = ((const float4*)w_hh)[idx - n1];
  if (idx < 2048) bcat[idx] = (idx < 512) ? b_h2h[idx] : b_hh[idx - 512];
}

__global__ __launch_bounds__(256) void init_kernel(float* __restrict__ h0,
                                                   int* __restrict__ tgt) {
  int idx = blockIdx.x * 256 + threadIdx.x;
  if (idx < NB * HH) h0[idx] = 0.f;
  if (idx < NB) tgt[idx] = 0;
}

extern "C" void kernel_launch(void* const* d_in, const int* in_sizes, int n_in,
                              void* d_out, int out_size, void* d_ws,
                              size_t ws_size, hipStream_t stream) {
  const float* feats = (const float*)d_in[0];
  const float* w_i2h = (const float*)d_in[1];
  const float* w_h2h = (const float*)d_in[2];
  const float* b_h2h = (const float*)d_in[3];
  const float* w_score = (const float*)d_in[4];
  const float* w_ih = (const float*)d_in[5];
  const float* w_hh = (const float*)d_in[6];
  const float* b_ih = (const float*)d_in[7];
  const float* b_hh = (const float*)d_in[8];
  const float* char_emb = (const float*)d_in[9];
  const float* w_gen = (const float*)d_in[10];
  const float* b_gen = (const float*)d_in[11];
  const int* tl = (const int*)d_in[12];
  float* out = (float*)d_out;

  char* ws = (char*)d_ws;
  float* fp = (float*)ws;      ws += (size_t)NT * NB * HH * 4;  // 134 MB
  float* C1a = (float*)ws;     ws += (size_t)NB * 2048 * 4;
  float* C1b = (float*)ws;     ws += (size_t)NB * 2048 * 4;
  float* Ga = (float*)ws;      ws += (size_t)NB * 1536 * 4;
  float* Gb = (float*)ws;      ws += (size_t)NB * 1536 * 4;
  float* context = (float*)ws; ws += (size_t)NB * NC * 4;
  float* h0 = (float*)ws;      ws += (size_t)NB * HH * 4;
  float* h1 = (float*)ws;      ws += (size_t)NB * HH * 4;
  float* Wcat = (float*)ws;    ws += (size_t)2048 * 512 * 4;
  float* bcat = (float*)ws;    ws += 2048 * 4;
  float* P = (float*)ws;       ws += (size_t)98 * 1536 * 4;
  int* tgt = (int*)ws;         ws += 4096;
  int* offs = (int*)ws;        ws += 4096;
  int* perm = (int*)ws;        ws += 4096;
  int* cnt = (int*)ws;         ws += 4096;

  hipLaunchKernelGGL(sort_tl, dim3(1), dim3(1024), 0, stream, tl, perm, cnt,
                     offs);
  hipLaunchKernelGGL(init_kernel, dim3((NB * HH) / 256), dim3(256), 0, stream,
                     h0, tgt);
  hipLaunchKernelGGL(build_wcat, dim3(1024), dim3(256), 0, stream, w_h2h, w_hh,
                     b_h2h, b_hh, Wcat, bcat);
  hipLaunchKernelGGL(build_P, dim3(98), dim3(256), 0, stream, char_emb, w_ih,
                     b_ih, P);
  // fp = feats @ w_i2h^T  [65536, 512]
  hipLaunchKernelGGL(gemm_bt_128p, dim3(HH / 128, (NT * NB) / 128), dim3(256),
                     0, stream, feats, w_i2h, fp, NT * NB, HH, NC);

  float* hbuf[2] = {h0, h1};
  for (int s = 0; s < STEPS; ++s) {
    float* hc = hbuf[s & 1];
    float* hn = hbuf[(s + 1) & 1];
    // C1 = hcomp @ Wcat^T + bcat   [cnt(s),2048], K-split-2
    hipLaunchKernelGGL(gemm_bt_ks, dim3(2048 / 128, NB / 64, 2), dim3(256), 0,
                       stream, hc, HH, Wcat, 512, bcat, C1a, C1b, 2048, cnt,
                       s);
    hipLaunchKernelGGL(step_attn2, dim3(NB), dim3(512), 0, stream, fp, C1a,
                       C1b, w_score, feats, context, perm, cnt, s);
    // gi = context @ w_ih[:, :512]^T   [cnt(s),1536], K-split-2
    hipLaunchKernelGGL(gemm_bt_ks, dim3(1536 / 128, NB / 64, 2), dim3(256), 0,
                       stream, context, NC, w_ih, NC + EE,
                       (const float*)nullptr, Ga, Gb, 1536, cnt, s);
    hipLaunchKernelGGL(step_update2, dim3(NB), dim3(128), 0, stream, C1a, C1b,
                       Ga, Gb, P, hc, hn, w_gen, b_gen, offs, out, tgt, perm,
                       cnt, s);
  }
}